// Round 8
// baseline (336.469 us; speedup 1.0000x reference)
//
#include <hip/hip_runtime.h>

// ---------------------------------------------------------------------------
// 2-layer GCN forward, pull-mode, bf16 tables, MFMA GEMMs.
//
// R8: gather working-set split.  h stored as two column-halves h_a/h_b
// (12.8 MB each); gather1 runs as two passes, each touching one table ->
// higher L2 hit rate on the random gather (hit ~ C_eff/T, measured
// C_eff ~8 MB).  All gathers now use the 64-wide path (Q=8 lanes/row,
// G=8 edge slots).  hist/bucket_scatter edge reads int4-vectorized.
//
// ws (4B units): dinv[Np] rowptr[Np+4] counts[MAXBK*NB] bsum[128]
//   csr_src[E] tmpP[E] | h_a ushort[N*64] | h_b ushort[N*64]
//   | h1 ushort[N*128]   (h2 reuses h_a)
// ---------------------------------------------------------------------------

typedef unsigned int uint;
typedef unsigned short ushort;
typedef __attribute__((ext_vector_type(8))) short bf16x8;
typedef __attribute__((ext_vector_type(8))) ushort u16x8;
typedef __attribute__((ext_vector_type(4))) float f32x4;

#define BSHIFT 8          // nodes per bucket = 256
#define MAXBK  512        // max buckets (N <= 131072)
#define NB     256        // hist/scatter blocks
#define CAP    8192       // LDS-staged edges per bucket (avg ~4096)

__device__ inline ushort f2bf(float f) {
    uint u = __float_as_uint(f);
    return (ushort)((u + 0x7fffu + ((u >> 16) & 1u)) >> 16);  // RNE
}
__device__ inline float bf_lo(uint u) { return __uint_as_float(u << 16); }
__device__ inline float bf_hi(uint u) { return __uint_as_float(u & 0xffff0000u); }

// ---- pass 1: per-block bucket histogram (LDS atomics only) ----
__global__ __launch_bounds__(256) void hist_kernel(const int* __restrict__ tgt,
                                                   int* __restrict__ counts,
                                                   int E, int chunk, int nbk) {
    __shared__ int hist[MAXBK];
    int t = threadIdx.x, b = blockIdx.x;
    for (int i = t; i < nbk; i += 256) hist[i] = 0;
    __syncthreads();
    int s = b * chunk, e = min(E, s + chunk);
    int i = s + t * 4;
    for (; i + 3 < e; i += 1024) {
        int4 tv = *(const int4*)&tgt[i];
        atomicAdd(&hist[tv.x >> BSHIFT], 1);
        atomicAdd(&hist[tv.y >> BSHIFT], 1);
        atomicAdd(&hist[tv.z >> BSHIFT], 1);
        atomicAdd(&hist[tv.w >> BSHIFT], 1);
    }
    if (i < e)
        for (int k = i; k < e; ++k) atomicAdd(&hist[tgt[k] >> BSHIFT], 1);
    __syncthreads();
    for (int i2 = t; i2 < nbk; i2 += 256) counts[i2 * NB + b] = hist[i2];
}

// ---- scan step 1: per-1024 partial sums of counts ----
__global__ __launch_bounds__(256) void scan_partial(const int* __restrict__ in,
                                                    int* __restrict__ bsum, int M) {
    int t = threadIdx.x, b = blockIdx.x;
    int base = b * 1024 + t * 4;
    int s = 0;
#pragma unroll
    for (int k = 0; k < 4; ++k) s += (base + k < M) ? in[base + k] : 0;
#pragma unroll
    for (int off = 32; off > 0; off >>= 1) s += __shfl_down(s, off, 64);
    __shared__ int ws[4];
    if ((t & 63) == 0) ws[t >> 6] = s;
    __syncthreads();
    if (t == 0) bsum[b] = ws[0] + ws[1] + ws[2] + ws[3];
}

// ---- scan step 2: exclusive scan of counts in place (bsum prefix fused) ----
__global__ __launch_bounds__(256) void scan_final_counts(int* __restrict__ counts,
                                                         const int* __restrict__ bsum,
                                                         int M) {
    int t = threadIdx.x, b = blockIdx.x;
    int lane = t & 63, wid = t >> 6;
    int p = 0;
    for (int i = t; i < b; i += 256) p += bsum[i];
#pragma unroll
    for (int off = 32; off > 0; off >>= 1) p += __shfl_down(p, off, 64);
    __shared__ int ps[4];
    if (lane == 0) ps[wid] = p;
    __syncthreads();
    int pre = ps[0] + ps[1] + ps[2] + ps[3];

    int base = b * 1024 + t * 4;
    int d[4];
#pragma unroll
    for (int k = 0; k < 4; ++k) d[k] = (base + k < M) ? counts[base + k] : 0;
    int tot = d[0] + d[1] + d[2] + d[3];
    int incl = tot;
#pragma unroll
    for (int off = 1; off < 64; off <<= 1) {
        int u = __shfl_up(incl, off, 64);
        if (lane >= off) incl += u;
    }
    __shared__ int wsum[4];
    if (lane == 63) wsum[wid] = incl;
    __syncthreads();
    int woff = 0;
    for (int w = 0; w < wid; ++w) woff += wsum[w];
    int run = incl - tot + woff + pre;
#pragma unroll
    for (int k = 0; k < 4; ++k) {
        if (base + k < M) counts[base + k] = run;
        run += d[k];
    }
}

// ---- pass 2: scatter edges into bucket-contiguous packed tmp ----
__global__ __launch_bounds__(256) void bucket_scatter(const int* __restrict__ src,
                                                      const int* __restrict__ tgt,
                                                      const int* __restrict__ offsets,
                                                      int* __restrict__ tmpP,
                                                      int E, int chunk, int nbk) {
    __shared__ int cur[MAXBK];
    int t = threadIdx.x, b = blockIdx.x;
    for (int i = t; i < nbk; i += 256) cur[i] = offsets[i * NB + b];
    __syncthreads();
    int s = b * chunk, e = min(E, s + chunk);
    int i = s + t * 4;
    for (; i + 3 < e; i += 1024) {
        int4 sv = *(const int4*)&src[i];
        int4 tv = *(const int4*)&tgt[i];
        int p0 = atomicAdd(&cur[tv.x >> BSHIFT], 1);
        tmpP[p0] = (sv.x << BSHIFT) | (tv.x & 255);
        int p1 = atomicAdd(&cur[tv.y >> BSHIFT], 1);
        tmpP[p1] = (sv.y << BSHIFT) | (tv.y & 255);
        int p2 = atomicAdd(&cur[tv.z >> BSHIFT], 1);
        tmpP[p2] = (sv.z << BSHIFT) | (tv.z & 255);
        int p3 = atomicAdd(&cur[tv.w >> BSHIFT], 1);
        tmpP[p3] = (sv.w << BSHIFT) | (tv.w & 255);
    }
    if (i < e) {
        for (int k = i; k < e; ++k) {
            int tg = tgt[k];
            int p = atomicAdd(&cur[tg >> BSHIFT], 1);
            tmpP[p] = (src[k] << BSHIFT) | (tg & 255);
        }
    }
}

// ---- pass 3 (fused): per-bucket deg count + scan + rowptr/dinv + csr fill ----
__global__ __launch_bounds__(256) void bucket_finish(const int* __restrict__ tmpP,
                                                     const int* __restrict__ offsets,
                                                     int* __restrict__ rowptr,
                                                     float* __restrict__ dinv,
                                                     int* __restrict__ csr_src,
                                                     int N, int E, int nbk) {
    __shared__ int stage[CAP];
    __shared__ int cnt[256];
    __shared__ int wsum[4];
    int t = threadIdx.x, b = blockIdx.x;
    cnt[t] = 0;
    __syncthreads();
    int s = offsets[b * NB];
    int e = (b + 1 < nbk) ? offsets[(b + 1) * NB] : E;
    int m = e - s;
    for (int i = t; i < m; i += 256) {
        int ed = tmpP[s + i];
        if (i < CAP) stage[i] = ed;
        atomicAdd(&cnt[ed & 255], 1);
    }
    __syncthreads();
    int lane = t & 63, wid = t >> 6;
    int d = cnt[t];
    int incl = d;
#pragma unroll
    for (int off = 1; off < 64; off <<= 1) {
        int u = __shfl_up(incl, off, 64);
        if (lane >= off) incl += u;
    }
    if (lane == 63) wsum[wid] = incl;
    __syncthreads();
    int woff = 0;
    for (int w = 0; w < wid; ++w) woff += wsum[w];
    int excl = s + incl - d + woff;
    int node = b * 256 + t;
    if (node < N) {
        rowptr[node] = excl;
        dinv[node] = rsqrtf((float)d + 1.0f);  // +1 self-loop
    }
    if (b == nbk - 1 && t == 255) rowptr[N] = E;
    cnt[t] = excl;  // reuse as cursor
    __syncthreads();
    for (int i = t; i < m; i += 256) {
        int ed = (i < CAP) ? stage[i] : tmpP[s + i];
        int p = atomicAdd(&cnt[ed & 255], 1);
        csr_src[p] = ed >> BSHIFT;
    }
}

// ---- MFMA GEMM: A[N,128] @ W[128,M] -> bf16, cols<64 to C0, >=64 to C1 ----
// block = 256 (4 waves), 64 rows/block; v_mfma_f32_16x16x32_bf16.
template <int M, typename AT>
__global__ __launch_bounds__(256) void gemm_mfma(const AT* __restrict__ A,
                                                 const float* __restrict__ W,
                                                 ushort* __restrict__ C0,
                                                 ushort* __restrict__ C1, int N) {
    constexpr int WTS = 136;           // padded row stride (bf16)
    __shared__ ushort WT[M * WTS];     // WT[n][k] = W[k][n]
    const int tid = threadIdx.x;
    for (int i = tid; i < 128 * (M / 4); i += 256) {
        int k = i / (M / 4);
        int n0 = (i % (M / 4)) * 4;
        float4 w = *(const float4*)&W[k * M + n0];
        WT[(n0 + 0) * WTS + k] = f2bf(w.x);
        WT[(n0 + 1) * WTS + k] = f2bf(w.y);
        WT[(n0 + 2) * WTS + k] = f2bf(w.z);
        WT[(n0 + 3) * WTS + k] = f2bf(w.w);
    }
    __syncthreads();

    const int wv = tid >> 6, lane = tid & 63;
    const int quad = lane >> 4, mrow = lane & 15;
    int arow_i = blockIdx.x * 64 + wv * 16 + mrow;
    if (arow_i >= N) arow_i = N - 1;   // clamp loads; stores guarded
    const AT* arow = &A[(size_t)arow_i * 128];

    f32x4 acc[M / 16];
#pragma unroll
    for (int t = 0; t < M / 16; ++t) acc[t] = (f32x4){0.f, 0.f, 0.f, 0.f};

#pragma unroll
    for (int ks = 0; ks < 4; ++ks) {
        const int k0 = ks * 32 + quad * 8;
        bf16x8 af;
        if constexpr (sizeof(AT) == 4) {
            float4 a0 = *(const float4*)&arow[k0];
            float4 a1 = *(const float4*)&arow[k0 + 4];
            af[0] = (short)f2bf(a0.x); af[1] = (short)f2bf(a0.y);
            af[2] = (short)f2bf(a0.z); af[3] = (short)f2bf(a0.w);
            af[4] = (short)f2bf(a1.x); af[5] = (short)f2bf(a1.y);
            af[6] = (short)f2bf(a1.z); af[7] = (short)f2bf(a1.w);
        } else {
            af = *(const bf16x8*)&arow[k0];
        }
#pragma unroll
        for (int t = 0; t < M / 16; ++t) {
            int n = t * 16 + mrow;
            bf16x8 bfr = *(const bf16x8*)&WT[n * WTS + k0];
            acc[t] = __builtin_amdgcn_mfma_f32_16x16x32_bf16(af, bfr, acc[t], 0, 0, 0);
        }
    }

    const int orow0 = blockIdx.x * 64 + wv * 16 + quad * 4;
#pragma unroll
    for (int r = 0; r < 4; ++r) {
        int orow = orow0 + r;
        if (orow < N) {
#pragma unroll
            for (int t = 0; t < M / 16; ++t) {
                int c = t * 16 + mrow;
                ushort* Cp = (c < 64) ? C0 : C1;
                Cp[(size_t)orow * 64 + (c & 63)] = f2bf(acc[t][r]);
            }
        }
    }
}

// ---- pull gather over a 64-col bf16 table.  Q=8 lanes/row, G=8 slots.
// OS = output row stride; outv/bias pre-offset by column base.
template <bool RELU, bool OUTBF, int OS>
__global__ __launch_bounds__(256) void gather64(
    const ushort* __restrict__ h, const int* __restrict__ rowptr,
    const int* __restrict__ csr_src, const float* __restrict__ dinv,
    const float* __restrict__ bias, void* __restrict__ outv, int N) {
    const int wid = threadIdx.x >> 6, lane = threadIdx.x & 63;
    const int node = blockIdx.x * 4 + wid;
    if (node >= N) return;
    const int g = lane >> 3, q = lane & 7;
    const int qoff = q * 8;
    const int beg = rowptr[node], end = rowptr[node + 1];
    float acc[8] = {};

    for (int j = beg; j < end; j += 16) {  // 2 independent chains in flight
        int e0 = j + g, e1 = j + 8 + g;
        {
            bool v = e0 < end;
            int s = v ? csr_src[e0] : node;
            float w = v ? dinv[s] : 0.0f;
            uint4 hv = *(const uint4*)&h[(size_t)s * 64 + qoff];
            acc[0] += w * bf_lo(hv.x); acc[1] += w * bf_hi(hv.x);
            acc[2] += w * bf_lo(hv.y); acc[3] += w * bf_hi(hv.y);
            acc[4] += w * bf_lo(hv.z); acc[5] += w * bf_hi(hv.z);
            acc[6] += w * bf_lo(hv.w); acc[7] += w * bf_hi(hv.w);
        }
        {
            bool v = e1 < end;
            int s = v ? csr_src[e1] : node;
            float w = v ? dinv[s] : 0.0f;
            uint4 hv = *(const uint4*)&h[(size_t)s * 64 + qoff];
            acc[0] += w * bf_lo(hv.x); acc[1] += w * bf_hi(hv.x);
            acc[2] += w * bf_lo(hv.y); acc[3] += w * bf_hi(hv.y);
            acc[4] += w * bf_lo(hv.z); acc[5] += w * bf_hi(hv.z);
            acc[6] += w * bf_lo(hv.w); acc[7] += w * bf_hi(hv.w);
        }
    }
#pragma unroll
    for (int m = 8; m < 64; m <<= 1)
#pragma unroll
        for (int k = 0; k < 8; ++k) acc[k] += __shfl_xor(acc[k], m, 64);

    const float di = dinv[node];
    {   // self-loop
        uint4 hv = *(const uint4*)&h[(size_t)node * 64 + qoff];
        acc[0] += di * bf_lo(hv.x); acc[1] += di * bf_hi(hv.x);
        acc[2] += di * bf_lo(hv.y); acc[3] += di * bf_hi(hv.y);
        acc[4] += di * bf_lo(hv.z); acc[5] += di * bf_hi(hv.z);
        acc[6] += di * bf_lo(hv.w); acc[7] += di * bf_hi(hv.w);
    }
    if (g == 0) {
        float4 b0 = *(const float4*)&bias[qoff];
        float4 b1 = *(const float4*)&bias[qoff + 4];
        float r[8] = {di * acc[0] + b0.x, di * acc[1] + b0.y,
                      di * acc[2] + b0.z, di * acc[3] + b0.w,
                      di * acc[4] + b1.x, di * acc[5] + b1.y,
                      di * acc[6] + b1.z, di * acc[7] + b1.w};
        if (RELU) {
#pragma unroll
            for (int k = 0; k < 8; ++k) r[k] = fmaxf(r[k], 0.0f);
        }
        if constexpr (OUTBF) {
            ushort* out = (ushort*)outv;
            u16x8 o;
#pragma unroll
            for (int k = 0; k < 8; ++k) o[k] = f2bf(r[k]);
            *(u16x8*)&out[(size_t)node * OS + qoff] = o;
        } else {
            float* out = (float*)outv;
            *(float4*)&out[(size_t)node * OS + qoff]     = make_float4(r[0], r[1], r[2], r[3]);
            *(float4*)&out[(size_t)node * OS + qoff + 4] = make_float4(r[4], r[5], r[6], r[7]);
        }
    }
}

extern "C" void kernel_launch(void* const* d_in, const int* in_sizes, int n_in,
                              void* d_out, int out_size, void* d_ws, size_t ws_size,
                              hipStream_t stream) {
    const float* x  = (const float*)d_in[0];
    const int*   ei = (const int*)d_in[1];
    const float* W1 = (const float*)d_in[2];
    const float* b1 = (const float*)d_in[3];
    const float* W2 = (const float*)d_in[4];
    const float* b2 = (const float*)d_in[5];
    float* out = (float*)d_out;

    const int N = in_sizes[0] / 128;
    const int E = in_sizes[1] / 2;
    const int* src = ei;
    const int* tgt = ei + E;

    const int nbk   = (N + 255) >> BSHIFT;               // buckets
    const int chunk = (((E + NB - 1) / NB) + 3) & ~3;    // ×4 for int4 alignment
    const int Mc    = nbk * NB;                          // counts length

    float* ws = (float*)d_ws;
    const size_t Np = (size_t)((N + 3) & ~3);
    float*  dinv    = ws;                            // Np
    int*    rowptr  = (int*)(ws + Np);               // Np+4
    int*    counts  = rowptr + Np + 4;               // MAXBK*NB (scanned in place)
    int*    bsum    = counts + MAXBK * NB;           // 128
    int*    csr_src = bsum + 128;                    // E
    int*    tmpP    = csr_src + E;                   // E packed (src<<8)|(tgt&255)
    ushort* h_a     = (ushort*)(tmpP + E);           // N*64 bf16 (cols 0..63)
    ushort* h_b     = h_a + (size_t)N * 64;          // N*64 bf16 (cols 64..127)
    ushort* h1      = h_b + (size_t)N * 64;          // N*128 bf16
    ushort* h2      = h_a;                           // reuse

    const int nbc = (Mc + 1023) / 1024;

    // CSR build — no global atomics, no memsets
    hist_kernel<<<NB, 256, 0, stream>>>(tgt, counts, E, chunk, nbk);
    scan_partial<<<nbc, 256, 0, stream>>>(counts, bsum, Mc);
    scan_final_counts<<<nbc, 256, 0, stream>>>(counts, bsum, Mc);
    bucket_scatter<<<NB, 256, 0, stream>>>(src, tgt, counts, tmpP, E, chunk, nbk);
    bucket_finish<<<nbk, 256, 0, stream>>>(tmpP, counts, rowptr, dinv, csr_src, N, E, nbk);

    // Layer 1: h = x@W1 split into h_a|h_b; two phase-separated gathers
    gemm_mfma<128, float><<<(N + 63) / 64, 256, 0, stream>>>(x, W1, h_a, h_b, N);
    gather64<true, true, 128><<<(N + 3) / 4, 256, 0, stream>>>(
        h_a, rowptr, csr_src, dinv, b1, h1, N);
    gather64<true, true, 128><<<(N + 3) / 4, 256, 0, stream>>>(
        h_b, rowptr, csr_src, dinv, b1 + 64, h1 + 64, N);

    // Layer 2
    gemm_mfma<64, ushort><<<(N + 63) / 64, 256, 0, stream>>>(h1, W2, h2, h2, N);
    gather64<false, false, 64><<<(N + 3) / 4, 256, 0, stream>>>(
        h2, rowptr, csr_src, dinv, b2, out, N);
}

// Round 9
// 310.510 us; speedup vs baseline: 1.0836x; 1.0836x over previous
//
#include <hip/hip_runtime.h>

// ---------------------------------------------------------------------------
// 2-layer GCN forward, pull-mode, bf16 tables, MFMA GEMMs.
//
// R9: (a) revert R8's table split (neutral on gather2, regressed gather1 --
// time ~ requests + bytes, split doubled gather1 requests).  (b) dinv
// pre-scaled into the gather tables at the GEMM epilogue (build precedes
// gemm1, so dinv is ready): h'[v] = dinv[v]*h[v].  Gather needs NO per-edge
// dinv load -> per-edge VMEM requests halved.
//   out[v] = dinv[v]*(sum_e h'[src] + h'[v]) + b
//
// ws (4B units): dinv[Np] rowptr[Np+4] counts[MAXBK*NB] bsum[128]
//   csr_src[E] tmpP[E] | h ushort[N*128] (reused as h2 ushort[N*64])
//   | h1 ushort[N*128]
// ---------------------------------------------------------------------------

typedef unsigned int uint;
typedef unsigned short ushort;
typedef __attribute__((ext_vector_type(8))) short bf16x8;
typedef __attribute__((ext_vector_type(8))) ushort u16x8;
typedef __attribute__((ext_vector_type(4))) float f32x4;

#define BSHIFT 8          // nodes per bucket = 256
#define MAXBK  512        // max buckets (N <= 131072)
#define NB     256        // hist/scatter blocks
#define CAP    8192       // LDS-staged edges per bucket (avg ~4096)

__device__ inline ushort f2bf(float f) {
    uint u = __float_as_uint(f);
    return (ushort)((u + 0x7fffu + ((u >> 16) & 1u)) >> 16);  // RNE
}
__device__ inline float bf_lo(uint u) { return __uint_as_float(u << 16); }
__device__ inline float bf_hi(uint u) { return __uint_as_float(u & 0xffff0000u); }

// ---- pass 1: per-block bucket histogram (LDS atomics only) ----
__global__ __launch_bounds__(256) void hist_kernel(const int* __restrict__ tgt,
                                                   int* __restrict__ counts,
                                                   int E, int chunk, int nbk) {
    __shared__ int hist[MAXBK];
    int t = threadIdx.x, b = blockIdx.x;
    for (int i = t; i < nbk; i += 256) hist[i] = 0;
    __syncthreads();
    int s = b * chunk, e = min(E, s + chunk);
    int i = s + t * 4;
    for (; i + 3 < e; i += 1024) {
        int4 tv = *(const int4*)&tgt[i];
        atomicAdd(&hist[tv.x >> BSHIFT], 1);
        atomicAdd(&hist[tv.y >> BSHIFT], 1);
        atomicAdd(&hist[tv.z >> BSHIFT], 1);
        atomicAdd(&hist[tv.w >> BSHIFT], 1);
    }
    if (i < e)
        for (int k = i; k < e; ++k) atomicAdd(&hist[tgt[k] >> BSHIFT], 1);
    __syncthreads();
    for (int i2 = t; i2 < nbk; i2 += 256) counts[i2 * NB + b] = hist[i2];
}

// ---- scan step 1: per-1024 partial sums of counts ----
__global__ __launch_bounds__(256) void scan_partial(const int* __restrict__ in,
                                                    int* __restrict__ bsum, int M) {
    int t = threadIdx.x, b = blockIdx.x;
    int base = b * 1024 + t * 4;
    int s = 0;
#pragma unroll
    for (int k = 0; k < 4; ++k) s += (base + k < M) ? in[base + k] : 0;
#pragma unroll
    for (int off = 32; off > 0; off >>= 1) s += __shfl_down(s, off, 64);
    __shared__ int ws[4];
    if ((t & 63) == 0) ws[t >> 6] = s;
    __syncthreads();
    if (t == 0) bsum[b] = ws[0] + ws[1] + ws[2] + ws[3];
}

// ---- scan step 2: exclusive scan of counts in place (bsum prefix fused) ----
__global__ __launch_bounds__(256) void scan_final_counts(int* __restrict__ counts,
                                                         const int* __restrict__ bsum,
                                                         int M) {
    int t = threadIdx.x, b = blockIdx.x;
    int lane = t & 63, wid = t >> 6;
    int p = 0;
    for (int i = t; i < b; i += 256) p += bsum[i];
#pragma unroll
    for (int off = 32; off > 0; off >>= 1) p += __shfl_down(p, off, 64);
    __shared__ int ps[4];
    if (lane == 0) ps[wid] = p;
    __syncthreads();
    int pre = ps[0] + ps[1] + ps[2] + ps[3];

    int base = b * 1024 + t * 4;
    int d[4];
#pragma unroll
    for (int k = 0; k < 4; ++k) d[k] = (base + k < M) ? counts[base + k] : 0;
    int tot = d[0] + d[1] + d[2] + d[3];
    int incl = tot;
#pragma unroll
    for (int off = 1; off < 64; off <<= 1) {
        int u = __shfl_up(incl, off, 64);
        if (lane >= off) incl += u;
    }
    __shared__ int wsum[4];
    if (lane == 63) wsum[wid] = incl;
    __syncthreads();
    int woff = 0;
    for (int w = 0; w < wid; ++w) woff += wsum[w];
    int run = incl - tot + woff + pre;
#pragma unroll
    for (int k = 0; k < 4; ++k) {
        if (base + k < M) counts[base + k] = run;
        run += d[k];
    }
}

// ---- pass 2: scatter edges into bucket-contiguous packed tmp ----
__global__ __launch_bounds__(256) void bucket_scatter(const int* __restrict__ src,
                                                      const int* __restrict__ tgt,
                                                      const int* __restrict__ offsets,
                                                      int* __restrict__ tmpP,
                                                      int E, int chunk, int nbk) {
    __shared__ int cur[MAXBK];
    int t = threadIdx.x, b = blockIdx.x;
    for (int i = t; i < nbk; i += 256) cur[i] = offsets[i * NB + b];
    __syncthreads();
    int s = b * chunk, e = min(E, s + chunk);
    int i = s + t * 4;
    for (; i + 3 < e; i += 1024) {
        int4 sv = *(const int4*)&src[i];
        int4 tv = *(const int4*)&tgt[i];
        int p0 = atomicAdd(&cur[tv.x >> BSHIFT], 1);
        tmpP[p0] = (sv.x << BSHIFT) | (tv.x & 255);
        int p1 = atomicAdd(&cur[tv.y >> BSHIFT], 1);
        tmpP[p1] = (sv.y << BSHIFT) | (tv.y & 255);
        int p2 = atomicAdd(&cur[tv.z >> BSHIFT], 1);
        tmpP[p2] = (sv.z << BSHIFT) | (tv.z & 255);
        int p3 = atomicAdd(&cur[tv.w >> BSHIFT], 1);
        tmpP[p3] = (sv.w << BSHIFT) | (tv.w & 255);
    }
    if (i < e) {
        for (int k = i; k < e; ++k) {
            int tg = tgt[k];
            int p = atomicAdd(&cur[tg >> BSHIFT], 1);
            tmpP[p] = (src[k] << BSHIFT) | (tg & 255);
        }
    }
}

// ---- pass 3 (fused): per-bucket deg count + scan + rowptr/dinv + csr fill ----
__global__ __launch_bounds__(256) void bucket_finish(const int* __restrict__ tmpP,
                                                     const int* __restrict__ offsets,
                                                     int* __restrict__ rowptr,
                                                     float* __restrict__ dinv,
                                                     int* __restrict__ csr_src,
                                                     int N, int E, int nbk) {
    __shared__ int stage[CAP];
    __shared__ int cnt[256];
    __shared__ int wsum[4];
    int t = threadIdx.x, b = blockIdx.x;
    cnt[t] = 0;
    __syncthreads();
    int s = offsets[b * NB];
    int e = (b + 1 < nbk) ? offsets[(b + 1) * NB] : E;
    int m = e - s;
    for (int i = t; i < m; i += 256) {
        int ed = tmpP[s + i];
        if (i < CAP) stage[i] = ed;
        atomicAdd(&cnt[ed & 255], 1);
    }
    __syncthreads();
    int lane = t & 63, wid = t >> 6;
    int d = cnt[t];
    int incl = d;
#pragma unroll
    for (int off = 1; off < 64; off <<= 1) {
        int u = __shfl_up(incl, off, 64);
        if (lane >= off) incl += u;
    }
    if (lane == 63) wsum[wid] = incl;
    __syncthreads();
    int woff = 0;
    for (int w = 0; w < wid; ++w) woff += wsum[w];
    int excl = s + incl - d + woff;
    int node = b * 256 + t;
    if (node < N) {
        rowptr[node] = excl;
        dinv[node] = rsqrtf((float)d + 1.0f);  // +1 self-loop
    }
    if (b == nbk - 1 && t == 255) rowptr[N] = E;
    cnt[t] = excl;  // reuse as cursor
    __syncthreads();
    for (int i = t; i < m; i += 256) {
        int ed = (i < CAP) ? stage[i] : tmpP[s + i];
        int p = atomicAdd(&cnt[ed & 255], 1);
        csr_src[p] = ed >> BSHIFT;
    }
}

// ---- MFMA GEMM: C[N,M](bf16) = dinv[row] * (A[N,128] @ W[128,M]) ----
// block = 256 (4 waves), 64 rows/block; v_mfma_f32_16x16x32_bf16.
// AT = float (convert in-flight) or ushort (bf16, load direct).
template <int M, typename AT>
__global__ __launch_bounds__(256) void gemm_mfma(const AT* __restrict__ A,
                                                 const float* __restrict__ W,
                                                 const float* __restrict__ dinv,
                                                 ushort* __restrict__ C, int N) {
    constexpr int WTS = 136;           // padded row stride (bf16)
    __shared__ ushort WT[M * WTS];     // WT[n][k] = W[k][n]
    const int tid = threadIdx.x;
    for (int i = tid; i < 128 * (M / 4); i += 256) {
        int k = i / (M / 4);
        int n0 = (i % (M / 4)) * 4;
        float4 w = *(const float4*)&W[k * M + n0];
        WT[(n0 + 0) * WTS + k] = f2bf(w.x);
        WT[(n0 + 1) * WTS + k] = f2bf(w.y);
        WT[(n0 + 2) * WTS + k] = f2bf(w.z);
        WT[(n0 + 3) * WTS + k] = f2bf(w.w);
    }
    __syncthreads();

    const int wv = tid >> 6, lane = tid & 63;
    const int quad = lane >> 4, mrow = lane & 15;
    int arow_i = blockIdx.x * 64 + wv * 16 + mrow;
    if (arow_i >= N) arow_i = N - 1;   // clamp loads; stores guarded
    const AT* arow = &A[(size_t)arow_i * 128];

    f32x4 acc[M / 16];
#pragma unroll
    for (int t = 0; t < M / 16; ++t) acc[t] = (f32x4){0.f, 0.f, 0.f, 0.f};

#pragma unroll
    for (int ks = 0; ks < 4; ++ks) {
        const int k0 = ks * 32 + quad * 8;
        bf16x8 af;
        if constexpr (sizeof(AT) == 4) {
            float4 a0 = *(const float4*)&arow[k0];
            float4 a1 = *(const float4*)&arow[k0 + 4];
            af[0] = (short)f2bf(a0.x); af[1] = (short)f2bf(a0.y);
            af[2] = (short)f2bf(a0.z); af[3] = (short)f2bf(a0.w);
            af[4] = (short)f2bf(a1.x); af[5] = (short)f2bf(a1.y);
            af[6] = (short)f2bf(a1.z); af[7] = (short)f2bf(a1.w);
        } else {
            af = *(const bf16x8*)&arow[k0];
        }
#pragma unroll
        for (int t = 0; t < M / 16; ++t) {
            int n = t * 16 + mrow;
            bf16x8 bfr = *(const bf16x8*)&WT[n * WTS + k0];
            acc[t] = __builtin_amdgcn_mfma_f32_16x16x32_bf16(af, bfr, acc[t], 0, 0, 0);
        }
    }

    const int orow0 = blockIdx.x * 64 + wv * 16 + quad * 4;
#pragma unroll
    for (int r = 0; r < 4; ++r) {
        int orow = orow0 + r;
        if (orow < N) {
            float dv = dinv[orow];   // pre-scale row into the gather table
#pragma unroll
            for (int t = 0; t < M / 16; ++t)
                C[(size_t)orow * M + t * 16 + mrow] = f2bf(dv * acc[t][r]);
        }
    }
}

// ---- pull gather over pre-scaled table.  Q=D/8 lanes/row, G=64/Q slots.
// out[v] = dinv[v]*(sum h'[src] + h'[v]) + b;  no per-edge dinv load.
template <int D, bool RELU, bool OUTBF>
__global__ __launch_bounds__(256) void gather_kernel(
    const ushort* __restrict__ h, const int* __restrict__ rowptr,
    const int* __restrict__ csr_src, const float* __restrict__ dinv,
    const float* __restrict__ bias, void* __restrict__ outv, int N) {
    constexpr int Q = D / 8;   // lanes covering one row (16B bf16x8 per lane)
    constexpr int G = 64 / Q;  // concurrent edge slots per wave
    const int wid = threadIdx.x >> 6, lane = threadIdx.x & 63;
    const int node = blockIdx.x * 4 + wid;
    if (node >= N) return;
    const int g = lane / Q, q = lane % Q;
    const int qoff = q * 8;
    const int beg = rowptr[node], end = rowptr[node + 1];
    float acc[8] = {};

    for (int j = beg; j < end; j += 2 * G) {  // 2 independent chains in flight
        int e0 = j + g, e1 = j + G + g;
        {
            bool v = e0 < end;
            int s = v ? csr_src[e0] : node;
            float m = v ? 1.0f : 0.0f;
            uint4 hv = *(const uint4*)&h[(size_t)s * D + qoff];
            acc[0] += m * bf_lo(hv.x); acc[1] += m * bf_hi(hv.x);
            acc[2] += m * bf_lo(hv.y); acc[3] += m * bf_hi(hv.y);
            acc[4] += m * bf_lo(hv.z); acc[5] += m * bf_hi(hv.z);
            acc[6] += m * bf_lo(hv.w); acc[7] += m * bf_hi(hv.w);
        }
        {
            bool v = e1 < end;
            int s = v ? csr_src[e1] : node;
            float m = v ? 1.0f : 0.0f;
            uint4 hv = *(const uint4*)&h[(size_t)s * D + qoff];
            acc[0] += m * bf_lo(hv.x); acc[1] += m * bf_hi(hv.x);
            acc[2] += m * bf_lo(hv.y); acc[3] += m * bf_hi(hv.y);
            acc[4] += m * bf_lo(hv.z); acc[5] += m * bf_hi(hv.z);
            acc[6] += m * bf_lo(hv.w); acc[7] += m * bf_hi(hv.w);
        }
    }
#pragma unroll
    for (int m2 = Q; m2 < 64; m2 <<= 1)
#pragma unroll
        for (int k = 0; k < 8; ++k) acc[k] += __shfl_xor(acc[k], m2, 64);

    {   // self-loop: + h'[node]
        uint4 hv = *(const uint4*)&h[(size_t)node * D + qoff];
        acc[0] += bf_lo(hv.x); acc[1] += bf_hi(hv.x);
        acc[2] += bf_lo(hv.y); acc[3] += bf_hi(hv.y);
        acc[4] += bf_lo(hv.z); acc[5] += bf_hi(hv.z);
        acc[6] += bf_lo(hv.w); acc[7] += bf_hi(hv.w);
    }
    if (g == 0) {
        const float di = dinv[node];
        float4 b0 = *(const float4*)&bias[qoff];
        float4 b1 = *(const float4*)&bias[qoff + 4];
        float r[8] = {di * acc[0] + b0.x, di * acc[1] + b0.y,
                      di * acc[2] + b0.z, di * acc[3] + b0.w,
                      di * acc[4] + b1.x, di * acc[5] + b1.y,
                      di * acc[6] + b1.z, di * acc[7] + b1.w};
        if (RELU) {
#pragma unroll
            for (int k = 0; k < 8; ++k) r[k] = fmaxf(r[k], 0.0f);
        }
        if constexpr (OUTBF) {
            ushort* out = (ushort*)outv;
            u16x8 o;
#pragma unroll
            for (int k = 0; k < 8; ++k) o[k] = f2bf(r[k]);
            *(u16x8*)&out[(size_t)node * D + qoff] = o;
        } else {
            float* out = (float*)outv;
            *(float4*)&out[(size_t)node * D + qoff]     = make_float4(r[0], r[1], r[2], r[3]);
            *(float4*)&out[(size_t)node * D + qoff + 4] = make_float4(r[4], r[5], r[6], r[7]);
        }
    }
}

extern "C" void kernel_launch(void* const* d_in, const int* in_sizes, int n_in,
                              void* d_out, int out_size, void* d_ws, size_t ws_size,
                              hipStream_t stream) {
    const float* x  = (const float*)d_in[0];
    const int*   ei = (const int*)d_in[1];
    const float* W1 = (const float*)d_in[2];
    const float* b1 = (const float*)d_in[3];
    const float* W2 = (const float*)d_in[4];
    const float* b2 = (const float*)d_in[5];
    float* out = (float*)d_out;

    const int N = in_sizes[0] / 128;
    const int E = in_sizes[1] / 2;
    const int* src = ei;
    const int* tgt = ei + E;

    const int nbk   = (N + 255) >> BSHIFT;               // buckets
    const int chunk = (((E + NB - 1) / NB) + 3) & ~3;    // ×4 for int4 alignment
    const int Mc    = nbk * NB;                          // counts length

    float* ws = (float*)d_ws;
    const size_t Np = (size_t)((N + 3) & ~3);
    float*  dinv    = ws;                            // Np
    int*    rowptr  = (int*)(ws + Np);               // Np+4
    int*    counts  = rowptr + Np + 4;               // MAXBK*NB (scanned in place)
    int*    bsum    = counts + MAXBK * NB;           // 128
    int*    csr_src = bsum + 128;                    // E
    int*    tmpP    = csr_src + E;                   // E packed (src<<8)|(tgt&255)
    ushort* h       = (ushort*)(tmpP + E);           // N*128 bf16 (reused as h2)
    ushort* h1      = h + (size_t)N * 128;           // N*128 bf16
    ushort* h2      = h;

    const int nbc = (Mc + 1023) / 1024;

    // CSR build — no global atomics, no memsets (produces rowptr/dinv/csr_src)
    hist_kernel<<<NB, 256, 0, stream>>>(tgt, counts, E, chunk, nbk);
    scan_partial<<<nbc, 256, 0, stream>>>(counts, bsum, Mc);
    scan_final_counts<<<nbc, 256, 0, stream>>>(counts, bsum, Mc);
    bucket_scatter<<<NB, 256, 0, stream>>>(src, tgt, counts, tmpP, E, chunk, nbk);
    bucket_finish<<<nbk, 256, 0, stream>>>(tmpP, counts, rowptr, dinv, csr_src, N, E, nbk);

    // Layer 1: h' = dinv * (x@W1)  (scaled in epilogue); gather; h1 = relu(...)
    gemm_mfma<128, float><<<(N + 63) / 64, 256, 0, stream>>>(x, W1, dinv, h, N);
    gather_kernel<128, true, true><<<(N + 3) / 4, 256, 0, stream>>>(
        h, rowptr, csr_src, dinv, b1, h1, N);

    // Layer 2: h2' = dinv * (h1@W2); gather -> out fp32
    gemm_mfma<64, ushort><<<(N + 63) / 64, 256, 0, stream>>>(h1, W2, dinv, h2, N);
    gather_kernel<64, false, false><<<(N + 3) / 4, 256, 0, stream>>>(
        h2, rowptr, csr_src, dinv, b2, out, N);
}